// Round 13
// baseline (133.744 us; speedup 1.0000x reference)
//
#include <hip/hip_runtime.h>

#define LOGZERO (-1.0e10f)

constexpr int BS    = 16;
constexpr int XMAX  = 512;
constexpr int VOCAB = 4000;
constexpr int YMAX  = 64;
constexpr int PF    = 8;    // DP ring depth (LDS loads and mask stores)
constexpr int TCH   = 8;    // time-steps per gather block
constexpr int CH    = 16;   // backtrace chunks
constexpr int CL    = 32;   // steps per chunk (CH*CL = XMAX)

// output layout (flat float32, reference return order)
constexpr size_t AS_OFF = 0;                                       // aligned_seq [16][512]
constexpr size_t TM_OFF = (size_t)BS * XMAX;                       // trigger_mask [16][65][512]
constexpr size_t YL_OFF = TM_OFF + (size_t)BS * (YMAX + 1) * XMAX; // ylens+1 [16]
constexpr size_t SC_OFF = YL_OFF + BS;                             // score [16]
// gather writes packed lpp[t][j] (j=0..63 odd labels, j=64 blank) into the TM region;
// dp stages it to LDS; btfused overwrites the region with the real trigger_mask.
//
// d_ws layout per b (float units), stride 8192 floats:
//   [0,4096)   bp masks: per t {bE,s1m},{s2m,bX} (4 u64 = 32 B; 512 t = 16 KB)
//   [4096]     ist (int)
constexpr size_t WS_STRIDE_F = 8192;

__device__ __forceinline__ float dpp_shr1_f(float x, float fill) {
    // full-wave shift-down-by-1: lane i gets lane i-1's x; lane 0 gets `fill`
    return __int_as_float(__builtin_amdgcn_update_dpp(
        __float_as_int(fill), __float_as_int(x), 0x138 /*wave_shr:1*/, 0xF, 0xF, false));
}
__device__ __forceinline__ int dpp_shr1_i(int x, int fill) {
    return __builtin_amdgcn_update_dpp(fill, x, 0x138, 0xF, 0xF, false);
}

// ---------------- kernel 1: parallel gather of per-path log-probs ----------------
__global__ __launch_bounds__(64)
void gather_kernel(const float* __restrict__ ctc,
                   const int* __restrict__ ys,
                   const int* __restrict__ blank_p,
                   float* __restrict__ out)
{
    const int tc   = blockIdx.x;
    const int b    = blockIdx.y;
    const int lane = threadIdx.x;

    const int blank = blank_p[0];
    const int ysv   = ys[b * YMAX + lane];

    const float* base = ctc + ((size_t)b * XMAX + (size_t)tc * TCH) * VOCAB;

    float v[TCH];
    #pragma unroll
    for (int j = 0; j < TCH; ++j)
        v[j] = base[(size_t)j * VOCAB + ysv];
    const float bl = base[(size_t)(lane & (TCH - 1)) * VOCAB + blank];

    float* lpp = out + TM_OFF + (size_t)b * (YMAX + 1) * XMAX + (size_t)tc * TCH * 65;
    #pragma unroll
    for (int j = 0; j < TCH; ++j)
        lpp[(size_t)j * 65 + lane] = v[j];
    if (lane < TCH)
        lpp[(size_t)lane * 65 + 64] = bl;
}

// one DP time-step; K is a compile-time ring index.
// Ballot planes (wave-uniform u64s) land in a PF-deep VGPR ring; the store of
// ring slot K is only clobbered PF steps later -> countable vmcnt, latency hidden.
#define DP_BODY(K)                                                             \
{                                                                              \
    const float lpO = rO[K], lpB = rB[K];                                      \
    rO[K] = lppL[offO]; rB[K] = lppL[offB]; offO += 65; offB += 65;            \
    const float prevO = dpp_shr1_f(aO, LOGZERO);                               \
    const float m2v   = sameO ? LOGZERO : prevO;                               \
    const float b01   = fmaxf(aO, aE);                                         \
    ringA[K].x = __ballot(prevO > aE);                                         \
    ringA[K].y = __ballot(aE > aO);                                            \
    ringB[K].x = __ballot(m2v > b01);                                          \
    ringB[K].y = __ballot(aO > aX);                                            \
    aX = fmaxf(aX, aO) + lpB;                                                  \
    aO = fmaxf(b01, m2v) + lpO;                                                \
    aE = fmaxf(aE, prevO) + lpB;                                               \
    if (lane == 0) { mp[0] = ringA[K]; mp[1] = ringB[K]; }                     \
    mp += 2;                                                                   \
    ++t;                                                                       \
}

// ---------------- kernel 2: DP loop (masks -> d_ws, scores/ist at end) ----------------
__global__ __launch_bounds__(256)
void dp_loop_kernel(const int* __restrict__ src_size,
                    const int* __restrict__ ys,
                    const int* __restrict__ ylens,
                    const float* __restrict__ out_ro,   // lpp region (read-only here)
                    float* __restrict__ out,
                    float* __restrict__ ws)
{
    const int b    = blockIdx.x;
    const int tid  = threadIdx.x;          // wave 0 runs the DP
    const int lane = tid & 63;

    const int ss   = src_size[b];
    const int ylen = ylens[b];
    const int plen = 2 * ylen + 1;

    __shared__ __align__(16) float lppL[(XMAX + PF) * 65];  // 135 KB, sole LDS user

    const float* gbase = out_ro + TM_OFF + (size_t)b * (YMAX + 1) * XMAX;
    float*       wsb   = ws + (size_t)b * WS_STRIDE_F;

    // ---- stage packed lpp into LDS (all 4 waves) ----
    {
        const float4* src = (const float4*)gbase;
        float4* dst = (float4*)lppL;
        #pragma unroll 4
        for (int i = tid; i < XMAX * 65 / 4; i += 256)
            dst[i] = src[i];
    }
    __syncthreads();

    // ---- wave 0: sequential DP; ballot planes -> d_ws via register ring ----
    if (tid < 64) {
        const int  ysv    = ys[b * YMAX + lane];
        const int  ysPrev = dpp_shr1_i(ysv, -1);
        const bool sameO  = (ysv == ysPrev);   // odd-state l-2 transition forbidden

        ulonglong2* mp = (ulonglong2*)wsb;

        float rO[PF], rB[PF];
        #pragma unroll
        for (int k = 0; k < PF; ++k) {
            rO[k] = lppL[k * 65 + lane];
            rB[k] = lppL[k * 65 + 64];
        }

        ulonglong2 ringA[PF], ringB[PF];
        float aE = (lane == 0) ? 0.0f : LOGZERO;   // alpha[2i]
        float aO = LOGZERO;                        // alpha[2i+1]
        float aX = LOGZERO;                        // alpha[128] (lane 63 meaningful)
        int offO = PF * 65 + lane, offB = PF * 65 + 64;
        int t = 0;

        while (t + PF <= ss) {
            #pragma unroll
            for (int k = 0; k < PF; ++k) DP_BODY(k)
        }
        #pragma unroll
        for (int k = 0; k < PF; ++k) { if (t < ss) DP_BODY(k) }

        // final registers = alpha after ss steps
        const float s1 = (ylen == YMAX) ? __shfl(aX, 63) : __shfl(aE, ylen);
        const float s2 = __shfl(aO, ylen - 1);
        if (lane == 0) {
            out[SC_OFF + b] = fmaxf(s1, s2);
            out[YL_OFF + b] = (float)(ylen + 1);
            ((int*)wsb)[4096] = (s1 > s2) ? (plen - 1) : (plen - 2);   // ist
        }
    }
}

// pure one-step backward jump at time T from state s (boundary handled; no store)
__device__ __forceinline__ int jstep(const ulonglong2* __restrict__ Mflat,
                                     int T, int s, int ist, int ssm1)
{
    const ulonglong2 m0 = Mflat[2 * T + 0];   // {bE, s1m}
    const ulonglong2 m1 = Mflat[2 * T + 1];   // {s2m, bX}
    const int ct = (T == ssm1) ? ist : s;
    const int h  = (ct >> 1) & 63;
    const int bE = (int)((m0.x >> h) & 1ULL);
    const int b1 = (int)((m0.y >> h) & 1ULL);
    const int b2 = (int)((m1.x >> h) & 1ULL);
    const int bX = (int)((m1.y >> 63) & 1ULL);
    int code = (ct & 1) ? (b2 ? 2 : b1) : bE;
    code = (ct == 128) ? bX : code;
    code = (T >= 1 && T <= ssm1) ? code : 0;
    return ct - code;
}

// ---------------- kernel 3: PARALLEL backtrace + epilogue (fused) ----------------
__global__ __launch_bounds__(256)
void btfused_kernel(const int* __restrict__ src_size,
                    const int* __restrict__ ys,
                    const int* __restrict__ blank_p,
                    float* __restrict__ out,
                    const float* __restrict__ ws)
{
    const int b    = blockIdx.x;
    const int tid  = threadIdx.x;
    const int lane = tid & 63;

    const int blank = blank_p[0];
    const int ss    = src_size[b];

    __shared__ ulonglong2 MAB[XMAX * 2];          // 16 KB bp masks, flat [2t],[2t+1]
    __shared__ unsigned char E[CH][132];          // chunk exit maps (pad 132)
    __shared__ int CE[CH];                        // chunk entry states
    __shared__ int states[XMAX];
    __shared__ int trig[XMAX];
    __shared__ int ysL[YMAX];
    __shared__ int istS;

    const float* wsb   = ws + (size_t)b * WS_STRIDE_F;
    float*       gbase = out + TM_OFF + (size_t)b * (YMAX + 1) * XMAX;

    // ---- stage masks (16 KB) -> LDS; ist; labels ----
    {
        const float4* src = (const float4*)wsb;
        float4* dst = (float4*)MAB;
        for (int i = tid; i < XMAX * 2; i += 256)
            dst[i] = src[i];
    }
    if (tid < YMAX) ysL[tid] = ys[b * YMAX + tid];
    if (tid == 0)   istS = ((const int*)wsb)[4096];
    __syncthreads();

    const int ist  = istS;
    const int ssm1 = ss - 1;

    // ---- step A: chunk exit maps. 16 chunks x 130 entry slots = 2080 tasks;
    //      4 independent walks in flight per thread to hide LDS latency ----
    for (int base = tid; base < CH * 130; base += 1024) {
        int tk0 = base;
        int tk1 = min(base + 256, CH * 130 - 1);
        int tk2 = min(base + 512, CH * 130 - 1);
        int tk3 = min(base + 768, CH * 130 - 1);
        const int c0 = tk0 / 130, e0 = tk0 - c0 * 130;
        const int c1 = tk1 / 130, e1 = tk1 - c1 * 130;
        const int c2 = tk2 / 130, e2 = tk2 - c2 * 130;
        const int c3 = tk3 / 130, e3 = tk3 - c3 * 130;
        int s0 = min(e0, 128), s1 = min(e1, 128), s2 = min(e2, 128), s3 = min(e3, 128);
        const int T0 = c0 * CL + CL - 1, T1 = c1 * CL + CL - 1;
        const int T2 = c2 * CL + CL - 1, T3 = c3 * CL + CL - 1;
        #pragma unroll
        for (int j = 0; j < CL; ++j) {
            s0 = jstep(MAB, T0 - j, s0, ist, ssm1);
            s1 = jstep(MAB, T1 - j, s1, ist, ssm1);
            s2 = jstep(MAB, T2 - j, s2, ist, ssm1);
            s3 = jstep(MAB, T3 - j, s3, ist, ssm1);
        }
        if (e0 <= 128)                        E[c0][e0] = (unsigned char)s0;
        if (e1 <= 128 && base + 256 < CH*130) E[c1][e1] = (unsigned char)s1;
        if (e2 <= 128 && base + 512 < CH*130) E[c2][e2] = (unsigned char)s2;
        if (e3 <= 128 && base + 768 < CH*130) E[c3][e3] = (unsigned char)s3;
    }
    __syncthreads();

    // ---- step B (thread 0): compose the 16 chunk maps (only serial remnant) ----
    if (tid == 0) {
        int cur = 0;
        for (int c = CH - 1; c >= 0; --c) {
            CE[c] = cur;
            cur = E[c][cur];
        }
    }
    __syncthreads();

    // ---- step C (lanes 0..15): re-walk own chunk writing states[t] ----
    if (tid < CH) {
        const int c = tid;
        int s = CE[c];
        for (int j = 0; j < CL; ++j) {
            const int T  = c * CL + CL - 1 - j;
            const int ct = (T == ssm1) ? ist : s;
            states[T] = (T <= ssm1) ? ct : 0;
            s = jstep(MAB, T, s, ist, ssm1);
        }
    }
    __syncthreads();

    // ---- phase F (wave 0): states -> labels, collapse, aligned_seq, trig scan ----
    if (tid < 64) {
        const int t8 = lane * 8;
        int sq[8];
        #pragma unroll
        for (int j = 0; j < 8; ++j) {
            const int st = states[t8 + j];
            sq[j] = (st & 1) ? ysL[st >> 1] : blank;
        }
        int prevLast = __shfl_up(sq[7], 1);
        if (lane == 0) prevLast = 0;

        int cl[8];
        #pragma unroll
        for (int j = 0; j < 8; ++j) {
            const int pv = j ? sq[j - 1] : prevLast;
            cl[j] = (sq[j] == pv) ? 0 : sq[j];
        }

        {   // aligned_seq out
            float* as = out + AS_OFF + (size_t)b * XMAX + t8;
            float4 o0, o1;
            o0.x = (float)cl[0]; o0.y = (float)cl[1]; o0.z = (float)cl[2]; o0.w = (float)cl[3];
            o1.x = (float)cl[4]; o1.y = (float)cl[5]; o1.z = (float)cl[6]; o1.w = (float)cl[7];
            *(float4*)as = o0; *((float4*)as + 1) = o1;
        }

        int cnt = 0;
        #pragma unroll
        for (int j = 0; j < 8; ++j) cnt += (cl[j] != blank);
        int x = cnt;
        #pragma unroll
        for (int d = 1; d < 64; d <<= 1) {
            const int y = __shfl_up(x, d);
            if (lane >= d) x += y;
        }
        int run = x - cnt + ((0 != blank) ? 1 : 0);
        #pragma unroll
        for (int j = 0; j < 8; ++j) {
            trig[t8 + j] = run;
            run += (cl[j] != blank);
        }
    }
    __syncthreads();

    // ---- phase G (all 256): trigger mask overwrites the lpp scratch region ----
    float* tm = gbase;
    for (int i4 = tid * 4; i4 < (YMAX + 1) * XMAX; i4 += 256 * 4) {
        const int y  = i4 >> 9;
        const int t0 = i4 & (XMAX - 1);
        const int4 tg4 = *(const int4*)&trig[t0];
        float4 v;
        if (y == YMAX) {
            v.x = ((tg4.x == YMAX && (t0 + 0) < ss) || (t0 + 0) == ss - 1) ? 1.0f : 0.0f;
            v.y = ((tg4.y == YMAX && (t0 + 1) < ss) || (t0 + 1) == ss - 1) ? 1.0f : 0.0f;
            v.z = ((tg4.z == YMAX && (t0 + 2) < ss) || (t0 + 2) == ss - 1) ? 1.0f : 0.0f;
            v.w = ((tg4.w == YMAX && (t0 + 3) < ss) || (t0 + 3) == ss - 1) ? 1.0f : 0.0f;
        } else {
            v.x = (tg4.x == y) ? 1.0f : 0.0f;
            v.y = (tg4.y == y) ? 1.0f : 0.0f;
            v.z = (tg4.z == y) ? 1.0f : 0.0f;
            v.w = (tg4.w == y) ? 1.0f : 0.0f;
        }
        *(float4*)(tm + i4) = v;
    }
}

extern "C" void kernel_launch(void* const* d_in, const int* in_sizes, int n_in,
                              void* d_out, int out_size, void* d_ws, size_t ws_size,
                              hipStream_t stream) {
    (void)in_sizes; (void)n_in; (void)ws_size; (void)out_size;
    const float* ctc      = (const float*)d_in[0];
    // d_in[1] = src_mask — derivable from src_size, unused
    const int*   src_size = (const int*)d_in[2];
    const int*   ys       = (const int*)d_in[3];
    const int*   ylens    = (const int*)d_in[4];
    const int*   blank    = (const int*)d_in[5];
    float*       out      = (float*)d_out;
    float*       ws       = (float*)d_ws;

    dim3 g1(XMAX / TCH, BS);
    gather_kernel<<<g1, 64, 0, stream>>>(ctc, ys, blank, out);
    dp_loop_kernel<<<BS, 256, 0, stream>>>(src_size, ys, ylens, out, out, ws);
    btfused_kernel<<<BS, 256, 0, stream>>>(src_size, ys, blank, out, ws);
}

// Round 15
// 86.644 us; speedup vs baseline: 1.5436x; 1.5436x over previous
//
#include <hip/hip_runtime.h>

#define LOGZERO (-1.0e10f)

constexpr int BS    = 16;
constexpr int XMAX  = 512;
constexpr int VOCAB = 4000;
constexpr int YMAX  = 64;
constexpr int PF    = 8;    // lp LDS ring depth
constexpr int TCH   = 8;    // time-steps per gather block
constexpr int GRP   = 16;   // DP steps per packed decision group
constexpr int NG    = XMAX / GRP;   // 32 groups
constexpr int CH    = 16;   // backtrace chunks
constexpr int CL    = 32;   // steps per chunk

// output layout (flat float32, reference return order)
constexpr size_t AS_OFF = 0;                                       // aligned_seq [16][512]
constexpr size_t TM_OFF = (size_t)BS * XMAX;                       // trigger_mask [16][65][512]
constexpr size_t YL_OFF = TM_OFF + (size_t)BS * (YMAX + 1) * XMAX; // ylens+1 [16]
constexpr size_t SC_OFF = YL_OFF + BS;                             // score [16]
// gather writes packed lpp[t][j] (j=0..63 odd labels, j=64 blank) into the TM region;
// dp stages it to LDS; btfused overwrites the region with the real trigger_mask.
//
// d_ws per b (float units), stride 8192 floats (32 KB):
//   [0,4096)  D[g][lane] uint2: per lane, 16-step packed decisions
//             word0: bits j   = even-state(2*lane) shift-sel; bits 16+j = state-128 sel (lane 63)
//             word1: bits 2j+1:2j = odd-state(2*lane+1) code 0/1/2
//   [4096]    ist (int)
// EVERY byte of D is written EVERY call (wave 0 writes groups [0,g0); waves 1-3
// zero-fill [g0,NG)) -> replay-deterministic, no poisoned reads.
constexpr size_t WS_STRIDE_F = 8192;

__device__ __forceinline__ float dpp_shr1_f(float x, float fill) {
    // full-wave shift-down-by-1: lane i gets lane i-1's x; lane 0 gets `fill`
    return __int_as_float(__builtin_amdgcn_update_dpp(
        __float_as_int(fill), __float_as_int(x), 0x138 /*wave_shr:1*/, 0xF, 0xF, false));
}
__device__ __forceinline__ int dpp_shr1_i(int x, int fill) {
    return __builtin_amdgcn_update_dpp(fill, x, 0x138, 0xF, 0xF, false);
}
// identity DPP mov: real copy regalloc can't coalesce with the live source
__device__ __forceinline__ int dpp_id_i(int x) {
    return __builtin_amdgcn_update_dpp(0, x, 0xE4 /*quad_perm identity*/, 0xF, 0xF, false);
}

// ---------------- kernel 1: parallel gather of per-path log-probs ----------------
__global__ __launch_bounds__(64)
void gather_kernel(const float* __restrict__ ctc,
                   const int* __restrict__ ys,
                   const int* __restrict__ blank_p,
                   float* __restrict__ out)
{
    const int tc   = blockIdx.x;
    const int b    = blockIdx.y;
    const int lane = threadIdx.x;

    const int blank = blank_p[0];
    const int ysv   = ys[b * YMAX + lane];

    const float* base = ctc + ((size_t)b * XMAX + (size_t)tc * TCH) * VOCAB;

    float v[TCH];
    #pragma unroll
    for (int j = 0; j < TCH; ++j)
        v[j] = base[(size_t)j * VOCAB + ysv];
    const float bl = base[(size_t)(lane & (TCH - 1)) * VOCAB + blank];

    float* lpp = out + TM_OFF + (size_t)b * (YMAX + 1) * XMAX + (size_t)tc * TCH * 65;
    #pragma unroll
    for (int j = 0; j < TCH; ++j)
        lpp[(size_t)j * 65 + lane] = v[j];
    if (lane < TCH)
        lpp[(size_t)lane * 65 + 64] = bl;
}

// ---------------- kernel 2: DP loop, per-lane packed decisions -> d_ws ----------------
__global__ __launch_bounds__(256)
void dp_loop_kernel(const int* __restrict__ src_size,
                    const int* __restrict__ ys,
                    const int* __restrict__ ylens,
                    const float* __restrict__ out_ro,   // lpp region (read-only here)
                    float* __restrict__ out,
                    float* __restrict__ ws)
{
    const int b    = blockIdx.x;
    const int tid  = threadIdx.x;          // wave 0 runs the DP
    const int lane = tid & 63;

    const int ss    = src_size[b];
    const int ylen  = ylens[b];
    const int plen  = 2 * ylen + 1;
    const int ssm1  = ss - 1;
    const int g0    = (ss + GRP - 1) >> 4;   // groups the DP writes

    __shared__ __align__(16) float lppL[(XMAX + PF) * 65];  // 135 KB

    const float* gbase = out_ro + TM_OFF + (size_t)b * (YMAX + 1) * XMAX;
    float*       wsb   = ws + (size_t)b * WS_STRIDE_F;

    // ---- stage packed lpp into LDS (all 4 waves) ----
    {
        const float4* src = (const float4*)gbase;
        float4* dst = (float4*)lppL;
        #pragma unroll 4
        for (int i = tid; i < XMAX * 65 / 4; i += 256)
            dst[i] = src[i];
    }
    __syncthreads();

    if (tid < 64) {
        // ---- wave 0: sequential DP; per-lane packed decision words ----
        const int  ysv    = ys[b * YMAX + lane];
        const int  ysPrev = dpp_shr1_i(ysv, -1);
        const bool sameO  = (ysv == ysPrev);   // odd-state l-2 transition forbidden

        uint2* dgl = (uint2*)wsb + lane;       // &D[0][lane]

        float rO[PF], rB[PF];
        #pragma unroll
        for (int k = 0; k < PF; ++k) {
            rO[k] = lppL[k * 65 + lane];
            rB[k] = lppL[k * 65 + 64];
        }

        float aE = (lane == 0) ? 0.0f : LOGZERO;   // alpha[2i]
        float aO = LOGZERO;                        // alpha[2i+1]
        float aX = LOGZERO;                        // alpha[128] (lane 63 meaningful)
        float fE = LOGZERO, fO = LOGZERO, fX = LOGZERO;
        int offO = PF * 65 + lane, offB = PF * 65 + 64;

        const int SS16 = g0 << 4;              // padded step count (<= XMAX)
        for (int tb = 0; tb < SS16; tb += GRP) {
            unsigned w0 = 0u, w1 = 0u;
            #pragma unroll
            for (int j = 0; j < GRP; ++j) {
                const int K = j & (PF - 1);
                const float lpO = rO[K], lpB = rB[K];
                rO[K] = lppL[offO]; rB[K] = lppL[offB]; offO += 65; offB += 65;
                const float prevO = dpp_shr1_f(aO, LOGZERO);
                const float m2v   = sameO ? LOGZERO : prevO;
                const float b01   = fmaxf(aO, aE);
                int oIdx = (aE > aO) ? 1 : 0;          // m1 strictly beats m0
                oIdx = (m2v > b01) ? 2 : oIdx;         // m2 strictly beats both
                w0 |= (prevO > aE) ? (1u << j) : 0u;            // even-state sel
                w0 |= (aO > aX)   ? (1u << (16 + j)) : 0u;      // state-128 sel
                w1 |= ((unsigned)oIdx) << (2 * j);              // odd-state code
                aX = fmaxf(aX, aO) + lpB;
                aO = fmaxf(b01, m2v) + lpO;
                aE = fmaxf(aE, prevO) + lpB;
                const bool cap = (tb + j == ssm1);     // alpha after ss steps
                fE = cap ? aE : fE;
                fO = cap ? aO : fO;
                fX = cap ? aX : fX;
            }
            // coalesced full-wave store; DPP copies break store-source reuse
            uint2 sv;
            sv.x = (unsigned)dpp_id_i((int)w0);
            sv.y = (unsigned)dpp_id_i((int)w1);
            *dgl = sv;
            dgl += 64;
        }

        const float s1 = (ylen == YMAX) ? __shfl(fX, 63) : __shfl(fE, ylen);
        const float s2 = __shfl(fO, ylen - 1);
        if (lane == 0) {
            out[SC_OFF + b] = fmaxf(s1, s2);
            out[YL_OFF + b] = (float)(ylen + 1);
            ((int*)wsb)[4096] = (s1 > s2) ? (plen - 1) : (plen - 2);   // ist
        }
    } else {
        // ---- waves 1-3: zero-fill groups [g0, NG) (disjoint addresses) ----
        uint2 z; z.x = 0u; z.y = 0u;
        uint2* dz = (uint2*)wsb;
        for (int i = g0 * 64 + (tid - 64); i < NG * 64; i += 192)
            dz[i] = z;
    }
}

// pure one-step backward jump at time T from state s (packed-word format)
__device__ __forceinline__ int jstep(const uint2* __restrict__ DL,
                                     int T, int s, int ist, int ssm1)
{
    const int g  = T >> 4;
    const int j  = T & 15;
    const int ct = (T == ssm1) ? ist : s;
    const int l  = (ct >= 128) ? 63 : (ct >> 1);
    const uint2 w = DL[g * 64 + l];
    const int ce = (int)((w.x >> j) & 1u);
    const int co = (int)((w.y >> (2 * j)) & 3u);
    const int cx = (int)((w.x >> (16 + j)) & 1u);
    int code = (ct & 1) ? co : ce;
    code = (ct == 128) ? cx : code;
    code = (T >= 1 && T <= ssm1) ? code : 0;
    return ct - code;
}

// ---------------- kernel 3: PARALLEL backtrace + epilogue (fused) ----------------
__global__ __launch_bounds__(256)
void btfused_kernel(const int* __restrict__ src_size,
                    const int* __restrict__ ys,
                    const int* __restrict__ blank_p,
                    float* __restrict__ out,
                    const float* __restrict__ ws)
{
    const int b    = blockIdx.x;
    const int tid  = threadIdx.x;
    const int lane = tid & 63;

    const int blank = blank_p[0];
    const int ss    = src_size[b];

    __shared__ uint2 DL[NG * 64];       // 16 KB packed decisions
    __shared__ int   E[CH][130];        // chunk exit maps (int: dword stores)
    __shared__ int   CE[CH];            // chunk entry states
    __shared__ int   states[XMAX];
    __shared__ int   trig[XMAX];
    __shared__ int   ysL[YMAX];
    __shared__ int   istS;

    const float* wsb   = ws + (size_t)b * WS_STRIDE_F;
    float*       gbase = out + TM_OFF + (size_t)b * (YMAX + 1) * XMAX;

    // ---- stage D (16 KB) -> LDS; ist; labels ----
    {
        const float4* src = (const float4*)wsb;
        float4* dst = (float4*)DL;
        for (int i = tid; i < NG * 64 * 8 / 16; i += 256)
            dst[i] = src[i];
    }
    if (tid < YMAX) ysL[tid] = ys[b * YMAX + tid];
    if (tid == 0)   istS = ((const int*)wsb)[4096];
    __syncthreads();

    const int ist  = istS;
    const int ssm1 = ss - 1;

    // ---- step A: chunk exit maps. 2080 tasks = 4 x 520 exact split;
    //      4 independent walks per thread for latency hiding ----
    constexpr int TK4 = (CH * 130) / 4;   // 520
    for (int p = tid; p < TK4; p += 256) {
        const int tA = p, tB = p + TK4, tC = p + 2 * TK4, tD = p + 3 * TK4;
        const int cA = tA / 130, eA = tA - cA * 130;
        const int cB = tB / 130, eB = tB - cB * 130;
        const int cC = tC / 130, eC = tC - cC * 130;
        const int cD = tD / 130, eD = tD - cD * 130;
        int sA = min(eA, 128), sB = min(eB, 128), sC = min(eC, 128), sD = min(eD, 128);
        #pragma unroll 4
        for (int j = 0; j < CL; ++j) {
            sA = jstep(DL, cA * CL + (CL - 1) - j, sA, ist, ssm1);
            sB = jstep(DL, cB * CL + (CL - 1) - j, sB, ist, ssm1);
            sC = jstep(DL, cC * CL + (CL - 1) - j, sC, ist, ssm1);
            sD = jstep(DL, cD * CL + (CL - 1) - j, sD, ist, ssm1);
        }
        E[cA][eA] = sA; E[cB][eB] = sB; E[cC][eC] = sC; E[cD][eD] = sD;
    }
    __syncthreads();

    // ---- step B (thread 0): compose the 16 chunk maps ----
    if (tid == 0) {
        int cur = 0;
        for (int c = CH - 1; c >= 0; --c) {
            CE[c] = cur;
            cur = E[c][cur];
        }
    }
    __syncthreads();

    // ---- step C (threads 0..15): re-walk own chunk writing states[t] ----
    if (tid < CH) {
        int s = CE[tid];
        for (int j = 0; j < CL; ++j) {
            const int T  = tid * CL + (CL - 1) - j;
            const int ct = (T == ssm1) ? ist : s;
            states[T] = (T <= ssm1) ? ct : 0;
            s = jstep(DL, T, s, ist, ssm1);
        }
    }
    __syncthreads();

    // ---- phase F (wave 0): states -> labels, collapse, aligned_seq, trig scan ----
    if (tid < 64) {
        const int t8 = lane * 8;
        int sq[8];
        #pragma unroll
        for (int j = 0; j < 8; ++j) {
            const int st = states[t8 + j];
            sq[j] = (st & 1) ? ysL[st >> 1] : blank;
        }
        int prevLast = __shfl_up(sq[7], 1);
        if (lane == 0) prevLast = 0;

        int cl[8];
        #pragma unroll
        for (int j = 0; j < 8; ++j) {
            const int pv = j ? sq[j - 1] : prevLast;
            cl[j] = (sq[j] == pv) ? 0 : sq[j];
        }

        {   // aligned_seq out
            float* as = out + AS_OFF + (size_t)b * XMAX + t8;
            float4 o0, o1;
            o0.x = (float)cl[0]; o0.y = (float)cl[1]; o0.z = (float)cl[2]; o0.w = (float)cl[3];
            o1.x = (float)cl[4]; o1.y = (float)cl[5]; o1.z = (float)cl[6]; o1.w = (float)cl[7];
            *(float4*)as = o0; *((float4*)as + 1) = o1;
        }

        int cnt = 0;
        #pragma unroll
        for (int j = 0; j < 8; ++j) cnt += (cl[j] != blank);
        int x = cnt;
        #pragma unroll
        for (int d = 1; d < 64; d <<= 1) {
            const int y = __shfl_up(x, d);
            if (lane >= d) x += y;
        }
        int run = x - cnt + ((0 != blank) ? 1 : 0);
        #pragma unroll
        for (int j = 0; j < 8; ++j) {
            trig[t8 + j] = run;
            run += (cl[j] != blank);
        }
    }
    __syncthreads();

    // ---- phase G (all 256): trigger mask overwrites the lpp scratch region ----
    float* tm = gbase;
    for (int i4 = tid * 4; i4 < (YMAX + 1) * XMAX; i4 += 256 * 4) {
        const int y  = i4 >> 9;
        const int t0 = i4 & (XMAX - 1);
        const int4 tg4 = *(const int4*)&trig[t0];
        float4 v;
        if (y == YMAX) {
            v.x = ((tg4.x == YMAX && (t0 + 0) < ss) || (t0 + 0) == ss - 1) ? 1.0f : 0.0f;
            v.y = ((tg4.y == YMAX && (t0 + 1) < ss) || (t0 + 1) == ss - 1) ? 1.0f : 0.0f;
            v.z = ((tg4.z == YMAX && (t0 + 2) < ss) || (t0 + 2) == ss - 1) ? 1.0f : 0.0f;
            v.w = ((tg4.w == YMAX && (t0 + 3) < ss) || (t0 + 3) == ss - 1) ? 1.0f : 0.0f;
        } else {
            v.x = (tg4.x == y) ? 1.0f : 0.0f;
            v.y = (tg4.y == y) ? 1.0f : 0.0f;
            v.z = (tg4.z == y) ? 1.0f : 0.0f;
            v.w = (tg4.w == y) ? 1.0f : 0.0f;
        }
        *(float4*)(tm + i4) = v;
    }
}

extern "C" void kernel_launch(void* const* d_in, const int* in_sizes, int n_in,
                              void* d_out, int out_size, void* d_ws, size_t ws_size,
                              hipStream_t stream) {
    (void)in_sizes; (void)n_in; (void)ws_size; (void)out_size;
    const float* ctc      = (const float*)d_in[0];
    // d_in[1] = src_mask — derivable from src_size, unused
    const int*   src_size = (const int*)d_in[2];
    const int*   ys       = (const int*)d_in[3];
    const int*   ylens    = (const int*)d_in[4];
    const int*   blank    = (const int*)d_in[5];
    float*       out      = (float*)d_out;
    float*       ws       = (float*)d_ws;

    dim3 g1(XMAX / TCH, BS);
    gather_kernel<<<g1, 64, 0, stream>>>(ctc, ys, blank, out);
    dp_loop_kernel<<<BS, 256, 0, stream>>>(src_size, ys, ylens, out, out, ws);
    btfused_kernel<<<BS, 256, 0, stream>>>(src_size, ys, blank, out, ws);
}

// Round 16
// 79.352 us; speedup vs baseline: 1.6855x; 1.0919x over previous
//
#include <hip/hip_runtime.h>

#define LOGZERO (-1.0e10f)

constexpr int BS    = 16;
constexpr int XMAX  = 512;
constexpr int VOCAB = 4000;
constexpr int YMAX  = 64;
constexpr int PF    = 8;    // lp LDS ring depth
constexpr int TCH   = 8;    // time-steps per gather block
constexpr int GRP   = 16;   // DP steps per packed decision group
constexpr int NG    = XMAX / GRP;   // 32 groups
constexpr int CH    = 16;   // backtrace chunks
constexpr int CL    = 32;   // steps per chunk

// output layout (flat float32, reference return order)
constexpr size_t AS_OFF = 0;                                       // aligned_seq [16][512]
constexpr size_t TM_OFF = (size_t)BS * XMAX;                       // trigger_mask [16][65][512]
constexpr size_t YL_OFF = TM_OFF + (size_t)BS * (YMAX + 1) * XMAX; // ylens+1 [16]
constexpr size_t SC_OFF = YL_OFF + BS;                             // score [16]
// gather writes packed lpp[t][j] (j=0..63 odd labels, j=64 blank) into the TM region;
// the fused kernel stages it to LDS and finally overwrites the region with the
// real trigger_mask. d_ws is unused this round (everything stays in LDS).

__device__ __forceinline__ float dpp_shr1_f(float x, float fill) {
    // full-wave shift-down-by-1: lane i gets lane i-1's x; lane 0 gets `fill`
    return __int_as_float(__builtin_amdgcn_update_dpp(
        __float_as_int(fill), __float_as_int(x), 0x138 /*wave_shr:1*/, 0xF, 0xF, false));
}
__device__ __forceinline__ int dpp_shr1_i(int x, int fill) {
    return __builtin_amdgcn_update_dpp(fill, x, 0x138, 0xF, 0xF, false);
}

// ---------------- kernel 1: parallel gather of per-path log-probs ----------------
__global__ __launch_bounds__(64)
void gather_kernel(const float* __restrict__ ctc,
                   const int* __restrict__ ys,
                   const int* __restrict__ blank_p,
                   float* __restrict__ out)
{
    const int tc   = blockIdx.x;
    const int b    = blockIdx.y;
    const int lane = threadIdx.x;

    const int blank = blank_p[0];
    const int ysv   = ys[b * YMAX + lane];

    const float* base = ctc + ((size_t)b * XMAX + (size_t)tc * TCH) * VOCAB;

    float v[TCH];
    #pragma unroll
    for (int j = 0; j < TCH; ++j)
        v[j] = base[(size_t)j * VOCAB + ysv];
    const float bl = base[(size_t)(lane & (TCH - 1)) * VOCAB + blank];

    float* lpp = out + TM_OFF + (size_t)b * (YMAX + 1) * XMAX + (size_t)tc * TCH * 65;
    #pragma unroll
    for (int j = 0; j < TCH; ++j)
        lpp[(size_t)j * 65 + lane] = v[j];
    if (lane < TCH)
        lpp[(size_t)lane * 65 + 64] = bl;
}

// one DP time-step; K = ring slot, J = bit position in the current group.
// ~17 VALU + 2 ds_read; no final-alpha capture (loop runs exactly ss steps).
#define DP_STEP(K, J)                                                          \
{                                                                              \
    const float lpO = rO[K], lpB = rB[K];                                      \
    rO[K] = lppL[offO]; rB[K] = lppL[offB]; offO += 65; offB += 65;            \
    const float prevO = dpp_shr1_f(aO, LOGZERO);                               \
    const float m2v   = sameO ? LOGZERO : prevO;                               \
    const float b01   = fmaxf(aO, aE);                                         \
    int oIdx = (aE > aO) ? 1 : 0;                                              \
    oIdx = (m2v > b01) ? 2 : oIdx;                                             \
    w0 |= (prevO > aE) ? (1u << (J)) : 0u;                                     \
    w0 |= (aO > aX)    ? (1u << (16 + (J))) : 0u;                              \
    w1 |= ((unsigned)oIdx) << (2 * (J));                                       \
    aX = fmaxf(aX, aO) + lpB;                                                  \
    aO = fmaxf(b01, m2v) + lpO;                                                \
    aE = fmaxf(aE, prevO) + lpB;                                               \
}

// pure one-step backward jump at time T from state s (packed-word format, LDS)
__device__ __forceinline__ int jstep(const uint2* DL, int T, int s, int ist, int ssm1)
{
    const int g  = T >> 4;
    const int j  = T & 15;
    const int ct = (T == ssm1) ? ist : s;
    const int l  = (ct >= 128) ? 63 : (ct >> 1);
    const uint2 w = DL[g * 64 + l];
    const int ce = (int)((w.x >> j) & 1u);
    const int co = (int)((w.y >> (2 * j)) & 3u);
    const int cx = (int)((w.x >> (16 + j)) & 1u);
    int code = (ct & 1) ? co : ce;
    code = (ct == 128) ? cx : code;
    code = (T >= 1 && T <= ssm1) ? code : 0;
    return ct - code;
}

// ---------------- kernel 2: fused DP + parallel backtrace + epilogue ----------------
__global__ __launch_bounds__(256)
void fused_kernel(const int* __restrict__ src_size,
                  const int* __restrict__ ys,
                  const int* __restrict__ ylens,
                  const int* __restrict__ blank_p,
                  float* __restrict__ out)
{
    const int b    = blockIdx.x;
    const int tid  = threadIdx.x;          // wave 0 runs the DP
    const int lane = tid & 63;

    const int blank = blank_p[0];
    const int ss    = src_size[b];
    const int ylen  = ylens[b];
    const int plen  = 2 * ylen + 1;
    const int ssm1  = ss - 1;
    const int gAll  = (ss + GRP - 1) >> 4;   // groups the DP writes

    // 135.2 KB region: lpp table during DP; E/states/trig alias it afterwards
    __shared__ __align__(16) char  smem[(XMAX + PF) * 65 * 4];
    __shared__ __align__(16) uint2 DLs[NG * 64];   // 16 KB packed decisions
    __shared__ int CE[CH];
    __shared__ int ysL[YMAX];
    __shared__ int istS;

    float* lppL   = (float*)smem;
    int*   E      = (int*)smem;                                   // [CH*130] post-DP
    int*   states = (int*)(smem + CH * 130 * 4);                  // [XMAX]
    int*   trig   = (int*)(smem + CH * 130 * 4 + XMAX * 4);       // [XMAX]

    float* gbase = out + TM_OFF + (size_t)b * (YMAX + 1) * XMAX;

    // ---- phase 0: stage packed lpp into LDS (all 4 waves) ----
    {
        const float4* src = (const float4*)gbase;
        float4* dst = (float4*)lppL;
        #pragma unroll 4
        for (int i = tid; i < XMAX * 65 / 4; i += 256)
            dst[i] = src[i];
    }
    if (tid < YMAX) ysL[tid] = ys[b * YMAX + tid];
    __syncthreads();

    if (tid < 64) {
        // ---- wave 0: sequential DP, packed decisions -> LDS (1 ds_write / 16 steps) ----
        const int  ysv    = ys[b * YMAX + lane];
        const int  ysPrev = dpp_shr1_i(ysv, -1);
        const bool sameO  = (ysv == ysPrev);   // odd-state l-2 transition forbidden

        float rO[PF], rB[PF];
        #pragma unroll
        for (int k = 0; k < PF; ++k) {
            rO[k] = lppL[k * 65 + lane];
            rB[k] = lppL[k * 65 + 64];
        }

        float aE = (lane == 0) ? 0.0f : LOGZERO;   // alpha[2i]
        float aO = LOGZERO;                        // alpha[2i+1]
        float aX = LOGZERO;                        // alpha[128] (lane 63 meaningful)
        int offO = PF * 65 + lane, offB = PF * 65 + 64;
        int t = 0, g = 0;

        while (t + GRP <= ss) {
            unsigned w0 = 0u, w1 = 0u;
            #pragma unroll
            for (int j = 0; j < GRP; ++j) { DP_STEP(j & (PF - 1), j) }
            t += GRP;
            uint2 sv; sv.x = w0; sv.y = w1;
            DLs[g * 64 + lane] = sv;
            ++g;
        }
        const int rem = ss - t;
        if (rem > 0) {
            unsigned w0 = 0u, w1 = 0u;
            #pragma unroll
            for (int j = 0; j < GRP; ++j) {
                if (j < rem) { DP_STEP(j & (PF - 1), j) }
            }
            uint2 sv; sv.x = w0; sv.y = w1;
            DLs[g * 64 + lane] = sv;
        }

        // final registers = alpha after exactly ss steps
        const float s1 = (ylen == YMAX) ? __shfl(aX, 63) : __shfl(aE, ylen);
        const float s2 = __shfl(aO, ylen - 1);
        if (lane == 0) {
            out[SC_OFF + b] = fmaxf(s1, s2);
            out[YL_OFF + b] = (float)(ylen + 1);
            istS = (s1 > s2) ? (plen - 1) : (plen - 2);
        }
    } else {
        // ---- waves 1-3: zero-fill decision groups [gAll, NG) (disjoint slots) ----
        uint2 z; z.x = 0u; z.y = 0u;
        for (int i = gAll * 64 + (tid - 64); i < NG * 64; i += 192)
            DLs[i] = z;
    }
    __syncthreads();

    const int ist = istS;

    // ---- step A: chunk exit maps. 2080 tasks = 4 x 520 split; 4 walks/thread ----
    constexpr int TK4 = (CH * 130) / 4;   // 520
    for (int p = tid; p < TK4; p += 256) {
        const int tA = p, tB = p + TK4, tC = p + 2 * TK4, tD = p + 3 * TK4;
        const int cA = tA / 130, eA = tA - cA * 130;
        const int cB = tB / 130, eB = tB - cB * 130;
        const int cC = tC / 130, eC = tC - cC * 130;
        const int cD = tD / 130, eD = tD - cD * 130;
        int sA = min(eA, 128), sB = min(eB, 128), sC = min(eC, 128), sD = min(eD, 128);
        #pragma unroll 4
        for (int j = 0; j < CL; ++j) {
            sA = jstep(DLs, cA * CL + (CL - 1) - j, sA, ist, ssm1);
            sB = jstep(DLs, cB * CL + (CL - 1) - j, sB, ist, ssm1);
            sC = jstep(DLs, cC * CL + (CL - 1) - j, sC, ist, ssm1);
            sD = jstep(DLs, cD * CL + (CL - 1) - j, sD, ist, ssm1);
        }
        E[cA * 130 + eA] = sA; E[cB * 130 + eB] = sB;
        E[cC * 130 + eC] = sC; E[cD * 130 + eD] = sD;
    }
    __syncthreads();

    // ---- step B (thread 0): compose the 16 chunk maps (only serial remnant) ----
    if (tid == 0) {
        int cur = 0;
        for (int c = CH - 1; c >= 0; --c) {
            CE[c] = cur;
            cur = E[c * 130 + cur];
        }
    }
    __syncthreads();

    // ---- step C (threads 0..15): re-walk own chunk writing states[t] ----
    if (tid < CH) {
        int s = CE[tid];
        for (int j = 0; j < CL; ++j) {
            const int T  = tid * CL + (CL - 1) - j;
            const int ct = (T == ssm1) ? ist : s;
            states[T] = (T <= ssm1) ? ct : 0;
            s = jstep(DLs, T, s, ist, ssm1);
        }
    }
    __syncthreads();

    // ---- phase F (wave 0): states -> labels, collapse, aligned_seq, trig scan ----
    if (tid < 64) {
        const int t8 = lane * 8;
        int sq[8];
        #pragma unroll
        for (int j = 0; j < 8; ++j) {
            const int st = states[t8 + j];
            sq[j] = (st & 1) ? ysL[st >> 1] : blank;
        }
        int prevLast = __shfl_up(sq[7], 1);
        if (lane == 0) prevLast = 0;

        int cl[8];
        #pragma unroll
        for (int j = 0; j < 8; ++j) {
            const int pv = j ? sq[j - 1] : prevLast;
            cl[j] = (sq[j] == pv) ? 0 : sq[j];
        }

        {   // aligned_seq out
            float* as = out + AS_OFF + (size_t)b * XMAX + t8;
            float4 o0, o1;
            o0.x = (float)cl[0]; o0.y = (float)cl[1]; o0.z = (float)cl[2]; o0.w = (float)cl[3];
            o1.x = (float)cl[4]; o1.y = (float)cl[5]; o1.z = (float)cl[6]; o1.w = (float)cl[7];
            *(float4*)as = o0; *((float4*)as + 1) = o1;
        }

        int cnt = 0;
        #pragma unroll
        for (int j = 0; j < 8; ++j) cnt += (cl[j] != blank);
        int x = cnt;
        #pragma unroll
        for (int d = 1; d < 64; d <<= 1) {
            const int y = __shfl_up(x, d);
            if (lane >= d) x += y;
        }
        int run = x - cnt + ((0 != blank) ? 1 : 0);
        #pragma unroll
        for (int j = 0; j < 8; ++j) {
            trig[t8 + j] = run;
            run += (cl[j] != blank);
        }
    }
    __syncthreads();

    // ---- phase G (all 256): trigger mask overwrites the lpp scratch region ----
    float* tm = gbase;
    for (int i4 = tid * 4; i4 < (YMAX + 1) * XMAX; i4 += 256 * 4) {
        const int y  = i4 >> 9;
        const int t0 = i4 & (XMAX - 1);
        const int4 tg4 = *(const int4*)&trig[t0];
        float4 v;
        if (y == YMAX) {
            v.x = ((tg4.x == YMAX && (t0 + 0) < ss) || (t0 + 0) == ss - 1) ? 1.0f : 0.0f;
            v.y = ((tg4.y == YMAX && (t0 + 1) < ss) || (t0 + 1) == ss - 1) ? 1.0f : 0.0f;
            v.z = ((tg4.z == YMAX && (t0 + 2) < ss) || (t0 + 2) == ss - 1) ? 1.0f : 0.0f;
            v.w = ((tg4.w == YMAX && (t0 + 3) < ss) || (t0 + 3) == ss - 1) ? 1.0f : 0.0f;
        } else {
            v.x = (tg4.x == y) ? 1.0f : 0.0f;
            v.y = (tg4.y == y) ? 1.0f : 0.0f;
            v.z = (tg4.z == y) ? 1.0f : 0.0f;
            v.w = (tg4.w == y) ? 1.0f : 0.0f;
        }
        *(float4*)(tm + i4) = v;
    }
}

extern "C" void kernel_launch(void* const* d_in, const int* in_sizes, int n_in,
                              void* d_out, int out_size, void* d_ws, size_t ws_size,
                              hipStream_t stream) {
    (void)in_sizes; (void)n_in; (void)d_ws; (void)ws_size; (void)out_size;
    const float* ctc      = (const float*)d_in[0];
    // d_in[1] = src_mask — derivable from src_size, unused
    const int*   src_size = (const int*)d_in[2];
    const int*   ys       = (const int*)d_in[3];
    const int*   ylens    = (const int*)d_in[4];
    const int*   blank    = (const int*)d_in[5];
    float*       out      = (float*)d_out;

    dim3 g1(XMAX / TCH, BS);
    gather_kernel<<<g1, 64, 0, stream>>>(ctc, ys, blank, out);
    fused_kernel<<<BS, 256, 0, stream>>>(src_size, ys, ylens, blank, out);
}

// Round 17
// 77.199 us; speedup vs baseline: 1.7325x; 1.0279x over previous
//
#include <hip/hip_runtime.h>

#define LOGZERO (-1.0e10f)

constexpr int BS    = 16;
constexpr int XMAX  = 512;
constexpr int VOCAB = 4000;
constexpr int YMAX  = 64;
constexpr int PF    = 8;    // lp LDS ring depth
constexpr int TCH   = 8;    // time-steps per gather block
constexpr int GRP   = 16;   // DP steps per packed decision group
constexpr int NG    = XMAX / GRP;   // 32 groups
constexpr int CH    = 16;   // backtrace chunks
constexpr int CL    = 32;   // steps per chunk

// output layout (flat float32, reference return order)
constexpr size_t AS_OFF = 0;                                       // aligned_seq [16][512]
constexpr size_t TM_OFF = (size_t)BS * XMAX;                       // trigger_mask [16][65][512]
constexpr size_t YL_OFF = TM_OFF + (size_t)BS * (YMAX + 1) * XMAX; // ylens+1 [16]
constexpr size_t SC_OFF = YL_OFF + BS;                             // score [16]
// gather writes packed lpp[t][j] (j=0..63 odd labels, j=64 blank) into the TM region
// for t < ss only (rows >= ss are never consumed by the DP); the fused kernel stages
// rows < ss+24 to LDS and finally overwrites the whole region with the trigger_mask,
// so the region's content is identical on every call (replay-deterministic).

__device__ __forceinline__ float dpp_shr1_f(float x, float fill) {
    // full-wave shift-down-by-1: lane i gets lane i-1's x; lane 0 gets `fill`
    return __int_as_float(__builtin_amdgcn_update_dpp(
        __float_as_int(fill), __float_as_int(x), 0x138 /*wave_shr:1*/, 0xF, 0xF, false));
}
__device__ __forceinline__ int dpp_shr1_i(int x, int fill) {
    return __builtin_amdgcn_update_dpp(fill, x, 0x138, 0xF, 0xF, false);
}

// ---------------- kernel 1: parallel gather of per-path log-probs ----------------
__global__ __launch_bounds__(64)
void gather_kernel(const float* __restrict__ ctc,
                   const int* __restrict__ ys,
                   const int* __restrict__ blank_p,
                   const int* __restrict__ src_size,
                   float* __restrict__ out)
{
    const int tc   = blockIdx.x;
    const int b    = blockIdx.y;
    const int lane = threadIdx.x;

    const int ss = src_size[b];
    if (tc * TCH >= ss) return;            // rows >= ss are never consumed

    const int blank = blank_p[0];
    const int ysv   = ys[b * YMAX + lane];

    const float* base = ctc + ((size_t)b * XMAX + (size_t)tc * TCH) * VOCAB;

    float v[TCH];
    #pragma unroll
    for (int j = 0; j < TCH; ++j)
        v[j] = base[(size_t)j * VOCAB + ysv];
    const float bl = base[(size_t)(lane & (TCH - 1)) * VOCAB + blank];

    float* lpp = out + TM_OFF + (size_t)b * (YMAX + 1) * XMAX + (size_t)tc * TCH * 65;
    #pragma unroll
    for (int j = 0; j < TCH; ++j)
        lpp[(size_t)j * 65 + lane] = v[j];
    if (lane < TCH)
        lpp[(size_t)lane * 65 + 64] = bl;
}

// one DP time-step; K = ring slot, J = bit position AND compile-time LDS row offset.
// Prefetch reads use group-base + 65*J so the 65*J*4 bytes fold into the ds_read
// immediate (no per-step address adds).
#define DP_STEP(K, J)                                                          \
{                                                                              \
    const float lpO = rO[K], lpB = rB[K];                                      \
    rO[K] = lppL[rowP  + 65 * (J)];                                            \
    rB[K] = lppL[rowPB + 65 * (J)];                                            \
    const float prevO = dpp_shr1_f(aO, LOGZERO);                               \
    const float m2v   = sameO ? LOGZERO : prevO;                               \
    const float b01   = fmaxf(aO, aE);                                         \
    int oIdx = (aE > aO) ? 1 : 0;                                              \
    oIdx = (m2v > b01) ? 2 : oIdx;                                             \
    w0 |= (prevO > aE) ? (1u << (J)) : 0u;                                     \
    w0 |= (aO > aX)    ? (1u << (16 + (J))) : 0u;                              \
    w1 |= ((unsigned)oIdx) << (2 * (J));                                       \
    aX = fmaxf(aX, aO) + lpB;                                                  \
    aO = fmaxf(b01, m2v) + lpO;                                                \
    aE = fmaxf(aE, prevO) + lpB;                                               \
}

// pure one-step backward jump at time T from state s (packed-word format, LDS)
__device__ __forceinline__ int jstep(const uint2* DL, int T, int s, int ist, int ssm1)
{
    const int g  = T >> 4;
    const int j  = T & 15;
    const int ct = (T == ssm1) ? ist : s;
    const int l  = (ct >= 128) ? 63 : (ct >> 1);
    const uint2 w = DL[g * 64 + l];
    const int ce = (int)((w.x >> j) & 1u);
    const int co = (int)((w.y >> (2 * j)) & 3u);
    const int cx = (int)((w.x >> (16 + j)) & 1u);
    int code = (ct & 1) ? co : ce;
    code = (ct == 128) ? cx : code;
    code = (T >= 1 && T <= ssm1) ? code : 0;
    return ct - code;
}

// ---------------- kernel 2: fused DP + parallel backtrace + epilogue ----------------
__global__ __launch_bounds__(256)
void fused_kernel(const int* __restrict__ src_size,
                  const int* __restrict__ ys,
                  const int* __restrict__ ylens,
                  const int* __restrict__ blank_p,
                  float* __restrict__ out)
{
    const int b    = blockIdx.x;
    const int tid  = threadIdx.x;          // wave 0 runs the DP
    const int lane = tid & 63;

    const int blank = blank_p[0];
    const int ss    = src_size[b];
    const int ylen  = ylens[b];
    const int plen  = 2 * ylen + 1;
    const int ssm1  = ss - 1;
    const int gAll  = (ss + GRP - 1) >> 4;   // groups the DP writes

    // 135.2 KB region: lpp table during DP; E/states/trig alias it afterwards
    __shared__ __align__(16) char  smem[(XMAX + PF) * 65 * 4];
    __shared__ __align__(16) uint2 DLs[NG * 64];   // 16 KB packed decisions
    __shared__ int CE[CH];
    __shared__ int ysL[YMAX];
    __shared__ int istS;

    float* lppL   = (float*)smem;
    int*   E      = (int*)smem;                                   // [CH*130] post-DP
    int*   states = (int*)(smem + CH * 130 * 4);                  // [XMAX]
    int*   trig   = (int*)(smem + CH * 130 * 4 + XMAX * 4);       // [XMAX]

    float* gbase = out + TM_OFF + (size_t)b * (YMAX + 1) * XMAX;

    // ---- phase 0: stage lpp rows < min(XMAX, ss+24) into LDS (all 4 waves) ----
    {
        const int nrows = min(XMAX, ss + PF + GRP);        // covers all ring reads
        const int n4    = (nrows * 65 + 3) / 4;
        const float4* src = (const float4*)gbase;
        float4* dst = (float4*)lppL;
        #pragma unroll 4
        for (int i = tid; i < n4; i += 256)
            dst[i] = src[i];
    }
    if (tid < YMAX) ysL[tid] = ys[b * YMAX + tid];
    __syncthreads();

    if (tid < 64) {
        // ---- wave 0: sequential DP, packed decisions -> LDS (1 ds_write / 16 steps) ----
        const int  ysv    = ys[b * YMAX + lane];
        const int  ysPrev = dpp_shr1_i(ysv, -1);
        const bool sameO  = (ysv == ysPrev);   // odd-state l-2 transition forbidden

        float rO[PF], rB[PF];
        #pragma unroll
        for (int k = 0; k < PF; ++k) {
            rO[k] = lppL[k * 65 + lane];
            rB[k] = lppL[k * 65 + 64];
        }

        float aE = (lane == 0) ? 0.0f : LOGZERO;   // alpha[2i]
        float aO = LOGZERO;                        // alpha[2i+1]
        float aX = LOGZERO;                        // alpha[128] (lane 63 meaningful)
        int rowP  = PF * 65 + lane;                // group prefetch base (odd col)
        int rowPB = PF * 65 + 64;                  // group prefetch base (blank col)
        int t = 0, g = 0;

        while (t + GRP <= ss) {
            unsigned w0 = 0u, w1 = 0u;
            #pragma unroll
            for (int j = 0; j < GRP; ++j) { DP_STEP(j & (PF - 1), j) }
            rowP += 65 * GRP; rowPB += 65 * GRP;
            t += GRP;
            uint2 sv; sv.x = w0; sv.y = w1;
            DLs[g * 64 + lane] = sv;
            ++g;
        }
        const int rem = ss - t;
        if (rem > 0) {
            unsigned w0 = 0u, w1 = 0u;
            #pragma unroll
            for (int j = 0; j < GRP; ++j) {
                if (j < rem) { DP_STEP(j & (PF - 1), j) }
            }
            uint2 sv; sv.x = w0; sv.y = w1;
            DLs[g * 64 + lane] = sv;
        }

        // final registers = alpha after exactly ss steps
        const float s1 = (ylen == YMAX) ? __shfl(aX, 63) : __shfl(aE, ylen);
        const float s2 = __shfl(aO, ylen - 1);
        if (lane == 0) {
            out[SC_OFF + b] = fmaxf(s1, s2);
            out[YL_OFF + b] = (float)(ylen + 1);
            istS = (s1 > s2) ? (plen - 1) : (plen - 2);
        }
    } else {
        // ---- waves 1-3: zero-fill decision groups [gAll, NG) (disjoint slots) ----
        uint2 z; z.x = 0u; z.y = 0u;
        for (int i = gAll * 64 + (tid - 64); i < NG * 64; i += 192)
            DLs[i] = z;
    }
    __syncthreads();

    const int ist = istS;

    // ---- step A: chunk exit maps. 2080 tasks = 4 x 520 split; 4 walks/thread ----
    constexpr int TK4 = (CH * 130) / 4;   // 520
    for (int p = tid; p < TK4; p += 256) {
        const int tA = p, tB = p + TK4, tC = p + 2 * TK4, tD = p + 3 * TK4;
        const int cA = tA / 130, eA = tA - cA * 130;
        const int cB = tB / 130, eB = tB - cB * 130;
        const int cC = tC / 130, eC = tC - cC * 130;
        const int cD = tD / 130, eD = tD - cD * 130;
        int sA = min(eA, 128), sB = min(eB, 128), sC = min(eC, 128), sD = min(eD, 128);
        #pragma unroll 4
        for (int j = 0; j < CL; ++j) {
            sA = jstep(DLs, cA * CL + (CL - 1) - j, sA, ist, ssm1);
            sB = jstep(DLs, cB * CL + (CL - 1) - j, sB, ist, ssm1);
            sC = jstep(DLs, cC * CL + (CL - 1) - j, sC, ist, ssm1);
            sD = jstep(DLs, cD * CL + (CL - 1) - j, sD, ist, ssm1);
        }
        E[cA * 130 + eA] = sA; E[cB * 130 + eB] = sB;
        E[cC * 130 + eC] = sC; E[cD * 130 + eD] = sD;
    }
    __syncthreads();

    // ---- step B (thread 0): compose the 16 chunk maps (only serial remnant) ----
    if (tid == 0) {
        int cur = 0;
        for (int c = CH - 1; c >= 0; --c) {
            CE[c] = cur;
            cur = E[c * 130 + cur];
        }
    }
    __syncthreads();

    // ---- step C (threads 0..15): re-walk own chunk writing states[t] ----
    if (tid < CH) {
        int s = CE[tid];
        for (int j = 0; j < CL; ++j) {
            const int T  = tid * CL + (CL - 1) - j;
            const int ct = (T == ssm1) ? ist : s;
            states[T] = (T <= ssm1) ? ct : 0;
            s = jstep(DLs, T, s, ist, ssm1);
        }
    }
    __syncthreads();

    // ---- phase F (wave 0): states -> labels, collapse, aligned_seq, trig scan ----
    if (tid < 64) {
        const int t8 = lane * 8;
        int sq[8];
        #pragma unroll
        for (int j = 0; j < 8; ++j) {
            const int st = states[t8 + j];
            sq[j] = (st & 1) ? ysL[st >> 1] : blank;
        }
        int prevLast = __shfl_up(sq[7], 1);
        if (lane == 0) prevLast = 0;

        int cl[8];
        #pragma unroll
        for (int j = 0; j < 8; ++j) {
            const int pv = j ? sq[j - 1] : prevLast;
            cl[j] = (sq[j] == pv) ? 0 : sq[j];
        }

        {   // aligned_seq out
            float* as = out + AS_OFF + (size_t)b * XMAX + t8;
            float4 o0, o1;
            o0.x = (float)cl[0]; o0.y = (float)cl[1]; o0.z = (float)cl[2]; o0.w = (float)cl[3];
            o1.x = (float)cl[4]; o1.y = (float)cl[5]; o1.z = (float)cl[6]; o1.w = (float)cl[7];
            *(float4*)as = o0; *((float4*)as + 1) = o1;
        }

        int cnt = 0;
        #pragma unroll
        for (int j = 0; j < 8; ++j) cnt += (cl[j] != blank);
        int x = cnt;
        #pragma unroll
        for (int d = 1; d < 64; d <<= 1) {
            const int y = __shfl_up(x, d);
            if (lane >= d) x += y;
        }
        int run = x - cnt + ((0 != blank) ? 1 : 0);
        #pragma unroll
        for (int j = 0; j < 8; ++j) {
            trig[t8 + j] = run;
            run += (cl[j] != blank);
        }
    }
    __syncthreads();

    // ---- phase G (all 256): trigger mask overwrites the lpp scratch region ----
    float* tm = gbase;
    for (int i4 = tid * 4; i4 < (YMAX + 1) * XMAX; i4 += 256 * 4) {
        const int y  = i4 >> 9;
        const int t0 = i4 & (XMAX - 1);
        const int4 tg4 = *(const int4*)&trig[t0];
        float4 v;
        if (y == YMAX) {
            v.x = ((tg4.x == YMAX && (t0 + 0) < ss) || (t0 + 0) == ss - 1) ? 1.0f : 0.0f;
            v.y = ((tg4.y == YMAX && (t0 + 1) < ss) || (t0 + 1) == ss - 1) ? 1.0f : 0.0f;
            v.z = ((tg4.z == YMAX && (t0 + 2) < ss) || (t0 + 2) == ss - 1) ? 1.0f : 0.0f;
            v.w = ((tg4.w == YMAX && (t0 + 3) < ss) || (t0 + 3) == ss - 1) ? 1.0f : 0.0f;
        } else {
            v.x = (tg4.x == y) ? 1.0f : 0.0f;
            v.y = (tg4.y == y) ? 1.0f : 0.0f;
            v.z = (tg4.z == y) ? 1.0f : 0.0f;
            v.w = (tg4.w == y) ? 1.0f : 0.0f;
        }
        *(float4*)(tm + i4) = v;
    }
}

extern "C" void kernel_launch(void* const* d_in, const int* in_sizes, int n_in,
                              void* d_out, int out_size, void* d_ws, size_t ws_size,
                              hipStream_t stream) {
    (void)in_sizes; (void)n_in; (void)d_ws; (void)ws_size; (void)out_size;
    const float* ctc      = (const float*)d_in[0];
    // d_in[1] = src_mask — derivable from src_size, unused
    const int*   src_size = (const int*)d_in[2];
    const int*   ys       = (const int*)d_in[3];
    const int*   ylens    = (const int*)d_in[4];
    const int*   blank    = (const int*)d_in[5];
    float*       out      = (float*)d_out;

    dim3 g1(XMAX / TCH, BS);
    gather_kernel<<<g1, 64, 0, stream>>>(ctc, ys, blank, src_size, out);
    fused_kernel<<<BS, 256, 0, stream>>>(src_size, ys, ylens, blank, out);
}